// Round 1
// baseline (164.278 us; speedup 1.0000x reference)
//
#include <hip/hip_runtime.h>
#include <math.h>

// ---------------------------------------------------------------------------
// CAM_Net fused pipeline, MI355X (gfx950)
//
// Stage layout in d_ws (floats):
//   x1   [32][256][256]   conv1 output
//   q    [32][256][256]   1x1 conv on x1
//   k    [32][262][262]   1x1 conv on pad3(x1)
//   v    [32][262][262]   1x1 conv on pad3(x1)
//   att  [32][256][256]   attention output (already un-scrambled)
//   sc   [32][32][32]     bilinear 256->32 (exact 2x2 average)
//   S    [38][9]          rect sums: [0..31]=scale window sums, [32..37]=x strided sums
//
// Tail trick: pooled mean of (backbone conv + expand conv) is linear ->
// collapses to 342 scalars + a 512x342 dot; backbone/expand convs never run.
// ---------------------------------------------------------------------------

#define OFF_X1  ((size_t)0)
#define OFF_Q   ((size_t)2097152)
#define OFF_K   ((size_t)4194304)
#define OFF_V   ((size_t)6390912)
#define OFF_ATT ((size_t)8587520)
#define OFF_SC  ((size_t)10684672)
#define OFF_S   ((size_t)10717440)
// total 10717782 floats ~= 42.9 MB

// K1: conv1 3x3 pad1, 6->32 channels, on x [6,256,256]
__global__ __launch_bounds__(256) void k_conv1(
    const float* __restrict__ x, const float* __restrict__ w,
    const float* __restrict__ b, float* __restrict__ x1) {
  int idx = blockIdx.x * 256 + threadIdx.x;     // 32*65536 threads
  int c  = idx >> 16;
  int y  = (idx >> 8) & 255;
  int xx = idx & 255;
  float acc = b[c];
  #pragma unroll
  for (int ci = 0; ci < 6; ++ci) {
    #pragma unroll
    for (int ky = 0; ky < 3; ++ky) {
      int iy = y - 1 + ky;
      if (iy < 0 || iy > 255) continue;
      #pragma unroll
      for (int kx = 0; kx < 3; ++kx) {
        int ix = xx - 1 + kx;
        if (ix < 0 || ix > 255) continue;
        acc = fmaf(w[((c * 6 + ci) * 3 + ky) * 3 + kx],
                   x[ci * 65536 + iy * 256 + ix], acc);
      }
    }
  }
  x1[idx] = acc;
}

// K2: fused 1x1 convs k/q/v. One thread per padded position, 8 out-channels
// per block-group (blockIdx&3) for occupancy. Weights are loop-uniform -> s_load.
__global__ __launch_bounds__(256) void k_qkv(
    const float* __restrict__ x1,
    const float* __restrict__ kw, const float* __restrict__ kb,
    const float* __restrict__ qw, const float* __restrict__ qb,
    const float* __restrict__ vw, const float* __restrict__ vb,
    float* __restrict__ kbuf, float* __restrict__ qbuf, float* __restrict__ vbuf) {
  int p  = (blockIdx.x >> 2) * 256 + threadIdx.x;
  int cg = blockIdx.x & 3;
  if (p >= 68644) return;                       // 262*262
  unsigned py = (unsigned)p / 262u;
  unsigned px = (unsigned)p - py * 262u;
  bool interior = (py >= 3u && py < 259u && px >= 3u && px < 259u);
  int iy = (int)py - 3, ix = (int)px - 3;
  float xv[32];
  #pragma unroll
  for (int ci = 0; ci < 32; ++ci)
    xv[ci] = interior ? x1[ci * 65536 + iy * 256 + ix] : 0.0f;
  #pragma unroll 1
  for (int c = cg * 8; c < cg * 8 + 8; ++c) {
    float ak = kb[c], av = vb[c], aq = qb[c];
    #pragma unroll
    for (int ci = 0; ci < 32; ++ci) {
      float xvv = xv[ci];
      ak = fmaf(kw[c * 32 + ci], xvv, ak);
      av = fmaf(vw[c * 32 + ci], xvv, av);
      aq = fmaf(qw[c * 32 + ci], xvv, aq);
    }
    kbuf[c * 68644 + p] = ak;
    vbuf[c * 68644 + p] = av;
    if (interior) qbuf[c * 65536 + iy * 256 + ix] = aq;
  }
}

// K3: attention. Block = (channel c, 4 rows h0..h0+3), 256 threads.
// Thread (ty=tid>>6, me=tid&63) handles group (c, h0+ty, w_base=4*me):
//   qk[i,j] = sum_d q[d]*k_pad[h+i, wb+d+j]  (+ qsum*(rh[i]+rw[j]))
//   softmax over 49, then out[d] = sum_z p[z]*v_pad[h+i, wb+d+j].
// LDS rows padded to 264 floats: 16B-aligned ds_read_b128, conflict-free.
__global__ __launch_bounds__(256) void k_attn(
    const float* __restrict__ kbuf, const float* __restrict__ qbuf,
    const float* __restrict__ vbuf, const float* __restrict__ relh,
    const float* __restrict__ relw, float* __restrict__ att) {
  __shared__ float ks[10 * 264];
  __shared__ float vs[10 * 264];
  __shared__ float qs[4 * 256];
  __shared__ float rhs[7];
  __shared__ float rws[7];
  int c  = blockIdx.x >> 6;
  int h0 = (blockIdx.x & 63) << 2;
  int tid = threadIdx.x;

  const float* kg = kbuf + c * 68644 + h0 * 262;
  const float* vg = vbuf + c * 68644 + h0 * 262;
  #pragma unroll
  for (int r = 0; r < 10; ++r) {
    for (int col = tid; col < 262; col += 256) {
      ks[r * 264 + col] = kg[r * 262 + col];
      vs[r * 264 + col] = vg[r * 262 + col];
    }
  }
  #pragma unroll
  for (int r = 0; r < 4; ++r)
    qs[r * 256 + tid] = qbuf[c * 65536 + (h0 + r) * 256 + tid];
  if (tid < 7) {
    float s = 0.f;
    for (int cc = 0; cc < 16; ++cc) s += relh[cc * 7 + tid];
    rhs[tid] = s;
  } else if (tid >= 8 && tid < 15) {
    int j = tid - 8;
    float s = 0.f;
    for (int cc = 0; cc < 16; ++cc) s += relw[cc * 7 + j];
    rws[j] = s;
  }
  __syncthreads();

  int me = tid & 63, ty = tid >> 6;
  int h = h0 + ty;
  float4 qv4 = *(const float4*)&qs[ty * 256 + me * 4];
  float qv0 = qv4.x, qv1 = qv4.y, qv2 = qv4.z, qv3 = qv4.w;
  float qsum = qv0 + qv1 + qv2 + qv3;

  float qk[49];
  #pragma unroll
  for (int i = 0; i < 7; ++i) {
    const float* krow = &ks[(ty + i) * 264 + me * 4];
    float kwin[12];
    *(float4*)&kwin[0] = *(const float4*)&krow[0];
    *(float4*)&kwin[4] = *(const float4*)&krow[4];
    *(float4*)&kwin[8] = *(const float4*)&krow[8];
    float rh = rhs[i];
    #pragma unroll
    for (int j = 0; j < 7; ++j) {
      float d0 = fmaf(qv0, kwin[j],
                 fmaf(qv1, kwin[j + 1],
                 fmaf(qv2, kwin[j + 2], qv3 * kwin[j + 3])));
      qk[i * 7 + j] = fmaf(qsum, rh + rws[j], d0);
    }
  }
  // max (tree-ish)
  float m = qk[0];
  #pragma unroll
  for (int z = 1; z < 49; ++z) m = fmaxf(m, qk[z]);
  float sum = 0.f;
  #pragma unroll
  for (int z = 0; z < 49; ++z) {
    float e = __expf(qk[z] - m);
    qk[z] = e;
    sum += e;
  }
  float inv = 1.0f / sum;

  float o0 = 0.f, o1 = 0.f, o2 = 0.f, o3 = 0.f;
  #pragma unroll
  for (int i = 0; i < 7; ++i) {
    const float* vrow = &vs[(ty + i) * 264 + me * 4];
    float vwin[12];
    *(float4*)&vwin[0] = *(const float4*)&vrow[0];
    *(float4*)&vwin[4] = *(const float4*)&vrow[4];
    *(float4*)&vwin[8] = *(const float4*)&vrow[8];
    #pragma unroll
    for (int j = 0; j < 7; ++j) {
      float p = qk[i * 7 + j];
      o0 = fmaf(p, vwin[j],     o0);
      o1 = fmaf(p, vwin[j + 1], o1);
      o2 = fmaf(p, vwin[j + 2], o2);
      o3 = fmaf(p, vwin[j + 3], o3);
    }
  }
  float4 out4 = make_float4(o0 * inv, o1 * inv, o2 * inv, o3 * inv);
  *(float4*)&att[c * 65536 + h * 256 + me * 4] = out4;
}

// K4: bilinear 256->32, align_corners=False: exact 2x2 average at (8o+3.5).
__global__ __launch_bounds__(256) void k_resize(
    const float* __restrict__ att, float* __restrict__ sc) {
  int idx = blockIdx.x * 256 + threadIdx.x;     // 32768
  int c = idx >> 10, oy = (idx >> 5) & 31, ox = idx & 31;
  int y0 = 8 * oy + 3, x0 = 8 * ox + 3;
  const float* a = att + c * 65536;
  sc[idx] = 0.25f * (a[y0 * 256 + x0] + a[y0 * 256 + x0 + 1] +
                     a[(y0 + 1) * 256 + x0] + a[(y0 + 1) * 256 + x0 + 1]);
}

// K5: the 342 linear-collapse sums.
//  b<32 : S[b][ky][kx]  = sum over out pos of sc[b, y-1+ky, x-1+kx] (zero pad)
//  b>=32: Sx[b-32][ky][kx] = sum over out pos of x[ci, 8oy-1+ky, 8ox-1+kx]
__global__ __launch_bounds__(256) void k_sums(
    const float* __restrict__ x, const float* __restrict__ sc,
    float* __restrict__ S) {
  int b = blockIdx.x, tid = threadIdx.x;
  float acc[9] = {0.f,0.f,0.f,0.f,0.f,0.f,0.f,0.f,0.f};
  if (b < 32) {
    const float* s = sc + b * 1024;
    for (int p = tid; p < 1024; p += 256) {
      int y = p >> 5, xx = p & 31;
      #pragma unroll
      for (int ky = 0; ky < 3; ++ky) {
        int iy = y + ky - 1;
        if (iy < 0 || iy > 31) continue;
        #pragma unroll
        for (int kx = 0; kx < 3; ++kx) {
          int ix = xx + kx - 1;
          if (ix < 0 || ix > 31) continue;
          acc[ky * 3 + kx] += s[iy * 32 + ix];
        }
      }
    }
  } else {
    const float* xc = x + (size_t)(b - 32) * 65536;
    for (int p = tid; p < 1024; p += 256) {
      int oy = p >> 5, ox = p & 31;
      #pragma unroll
      for (int ky = 0; ky < 3; ++ky) {
        int iy = 8 * oy - 1 + ky;
        if (iy < 0 || iy > 255) continue;
        #pragma unroll
        for (int kx = 0; kx < 3; ++kx) {
          int ix = 8 * ox - 1 + kx;
          if (ix < 0 || ix > 255) continue;
          acc[ky * 3 + kx] += xc[iy * 256 + ix];
        }
      }
    }
  }
  __shared__ float part[4][9];
  #pragma unroll
  for (int k = 0; k < 9; ++k) {
    #pragma unroll
    for (int off = 32; off >= 1; off >>= 1)
      acc[k] += __shfl_down(acc[k], off);
  }
  int wave = tid >> 6, lane = tid & 63;
  if (lane == 0) {
    #pragma unroll
    for (int k = 0; k < 9; ++k) part[wave][k] = acc[k];
  }
  __syncthreads();
  if (tid < 9)
    S[b * 9 + tid] = part[0][tid] + part[1][tid] + part[2][tid] + part[3][tid];
}

// K6: pooled[512] = bb+eb+(bw.Sx + ew.S)/1024, then fc -> out[20]. One block.
__global__ __launch_bounds__(512) void k_head(
    const float* __restrict__ S,
    const float* __restrict__ bw, const float* __restrict__ bb,
    const float* __restrict__ ew, const float* __restrict__ eb,
    const float* __restrict__ fcw, const float* __restrict__ fcb,
    float* __restrict__ out) {
  __shared__ float Sl[342];
  __shared__ float pl[512];
  int tid = threadIdx.x;
  if (tid < 342) Sl[tid] = S[tid];
  __syncthreads();
  int oc = tid;
  float acc = 0.f;
  #pragma unroll 1
  for (int ci = 0; ci < 32; ++ci) {
    #pragma unroll
    for (int k = 0; k < 9; ++k)
      acc = fmaf(ew[oc * 288 + ci * 9 + k], Sl[ci * 9 + k], acc);
  }
  #pragma unroll 1
  for (int ci = 0; ci < 6; ++ci) {
    #pragma unroll
    for (int k = 0; k < 9; ++k)
      acc = fmaf(bw[oc * 54 + ci * 9 + k], Sl[288 + ci * 9 + k], acc);
  }
  pl[oc] = bb[oc] + eb[oc] + acc * (1.0f / 1024.0f);
  __syncthreads();
  if (tid < 20) {
    float a = fcb[tid];
    for (int o2 = 0; o2 < 512; ++o2)
      a = fmaf(fcw[tid * 512 + o2], pl[o2], a);
    out[tid] = a;
  }
}

extern "C" void kernel_launch(void* const* d_in, const int* in_sizes, int n_in,
                              void* d_out, int out_size, void* d_ws, size_t ws_size,
                              hipStream_t stream) {
  const float* x    = (const float*)d_in[0];
  // d_in[1] = diff_input (int, always 1) -> attention branch always taken
  const float* bw   = (const float*)d_in[2];
  const float* bb   = (const float*)d_in[3];
  const float* c1w  = (const float*)d_in[4];
  const float* c1b  = (const float*)d_in[5];
  const float* kw   = (const float*)d_in[6];
  const float* kb   = (const float*)d_in[7];
  const float* qw   = (const float*)d_in[8];
  const float* qb   = (const float*)d_in[9];
  const float* vw   = (const float*)d_in[10];
  const float* vb   = (const float*)d_in[11];
  const float* relh = (const float*)d_in[12];
  const float* relw = (const float*)d_in[13];
  const float* ew   = (const float*)d_in[14];
  const float* eb   = (const float*)d_in[15];
  const float* fcw  = (const float*)d_in[16];
  const float* fcb  = (const float*)d_in[17];

  float* ws   = (float*)d_ws;
  float* x1   = ws + OFF_X1;
  float* qbuf = ws + OFF_Q;
  float* kbuf = ws + OFF_K;
  float* vbuf = ws + OFF_V;
  float* att  = ws + OFF_ATT;
  float* scb  = ws + OFF_SC;
  float* Sbuf = ws + OFF_S;
  float* out  = (float*)d_out;

  k_conv1 <<<8192, 256, 0, stream>>>(x, c1w, c1b, x1);
  k_qkv   <<<1076, 256, 0, stream>>>(x1, kw, kb, qw, qb, vw, vb, kbuf, qbuf, vbuf);
  k_attn  <<<2048, 256, 0, stream>>>(kbuf, qbuf, vbuf, relh, relw, att);
  k_resize<<<128,  256, 0, stream>>>(att, scb);
  k_sums  <<<38,   256, 0, stream>>>(x, scb, Sbuf);
  k_head  <<<1,    512, 0, stream>>>(Sbuf, bw, bb, ew, eb, fcw, fcb, out);
}

// Round 2
// 119.950 us; speedup vs baseline: 1.3696x; 1.3696x over previous
//
#include <hip/hip_runtime.h>
#include <math.h>

// ---------------------------------------------------------------------------
// CAM_Net fused pipeline, MI355X (gfx950) — round 2
//
// ws layout (floats):
//   q    [32][256][256]   fused conv1+1x1q output
//   k    [32][262][262]   fused conv1+1x1k on pad3
//   v    [32][262][262]   fused conv1+1x1v on pad3
//   att  [32][256][256]   attention output (un-scrambled closed form)
//   S    [342]            linear-collapse sums (32*9 scale + 6*9 x-strided)
//   pooled [512]
//
// x1 is never materialized: conv1 (3x3, 6->32) is computed per-pixel in
// registers and fed straight into the three 1x1 convs (k_front).
// backbone/expand convs never run (linear collapse -> k_pool/k_fc).
// bilinear 256->32 is an exact 2x2 average, folded into k_sums.
// ---------------------------------------------------------------------------

#define OFF_Q   ((size_t)0)
#define OFF_K   ((size_t)2097152)
#define OFF_V   ((size_t)4293760)
#define OFF_ATT ((size_t)6490368)
#define OFF_S   ((size_t)8587520)
#define OFF_P   ((size_t)8587904)
// total ~8.59M floats ~= 34.4 MB

// K1: fused conv1(3x3 pad1) + k/q/v 1x1 convs. One thread per padded pos.
__global__ __launch_bounds__(256) void k_front(
    const float* __restrict__ x,
    const float* __restrict__ c1w, const float* __restrict__ c1b,
    const float* __restrict__ kw, const float* __restrict__ kb,
    const float* __restrict__ qw, const float* __restrict__ qb,
    const float* __restrict__ vw, const float* __restrict__ vb,
    float* __restrict__ kbuf, float* __restrict__ qbuf, float* __restrict__ vbuf) {
  int p = blockIdx.x * 256 + threadIdx.x;
  if (p >= 68644) return;                       // 262*262
  unsigned py = (unsigned)p / 262u;
  unsigned px = (unsigned)p - py * 262u;
  bool interior = (py >= 3u && py < 259u && px >= 3u && px < 259u);
  if (!interior) {                              // x1 pad is zero -> bias only
    #pragma unroll 1
    for (int c = 0; c < 32; ++c) {
      kbuf[c * 68644 + p] = kb[c];
      vbuf[c * 68644 + p] = vb[c];
    }
    return;
  }
  int iy = (int)py - 3, ix = (int)px - 3;

  // conv1 in registers: xv[c] = x1[c] at (iy,ix)
  float xv[32];
  #pragma unroll
  for (int c = 0; c < 32; ++c) xv[c] = c1b[c];
  #pragma unroll 1
  for (int ci = 0; ci < 6; ++ci) {
    float patch[9];
    #pragma unroll
    for (int dy = 0; dy < 3; ++dy) {
      int yy = iy - 1 + dy;
      bool yok = (yy >= 0 && yy <= 255);
      #pragma unroll
      for (int dx = 0; dx < 3; ++dx) {
        int xx2 = ix - 1 + dx;
        bool ok = yok && (xx2 >= 0 && xx2 <= 255);
        patch[dy * 3 + dx] = ok ? x[ci * 65536 + yy * 256 + xx2] : 0.0f;
      }
    }
    #pragma unroll
    for (int c = 0; c < 32; ++c) {
      const float* wc = c1w + (c * 6 + ci) * 9;
      float s = xv[c];
      #pragma unroll
      for (int t = 0; t < 9; ++t) s = fmaf(wc[t], patch[t], s);
      xv[c] = s;
    }
  }

  // three 1x1 convs, streamed per out-channel
  int qidx = iy * 256 + ix;
  #pragma unroll 1
  for (int c = 0; c < 32; ++c) {
    float ak = kb[c], av = vb[c], aq = qb[c];
    #pragma unroll
    for (int ci = 0; ci < 32; ++ci) {
      float xvv = xv[ci];
      ak = fmaf(kw[c * 32 + ci], xvv, ak);
      av = fmaf(vw[c * 32 + ci], xvv, av);
      aq = fmaf(qw[c * 32 + ci], xvv, aq);
    }
    kbuf[c * 68644 + p] = ak;
    vbuf[c * 68644 + p] = av;
    qbuf[c * 65536 + qidx] = aq;
  }
}

// K2: attention. Block = (channel c, 4 rows), 256 threads; thread handles
// softmax group (c, h, w_base=4*(tid&63)). LDS rows padded to 264 floats:
// 16B-aligned ds_read_b128, conflict-free.
__global__ __launch_bounds__(256) void k_attn(
    const float* __restrict__ kbuf, const float* __restrict__ qbuf,
    const float* __restrict__ vbuf, const float* __restrict__ relh,
    const float* __restrict__ relw, float* __restrict__ att) {
  __shared__ float ks[10 * 264];
  __shared__ float vs[10 * 264];
  __shared__ float qs[4 * 256];
  __shared__ float rhs[7];
  __shared__ float rws[7];
  int c  = blockIdx.x >> 6;
  int h0 = (blockIdx.x & 63) << 2;
  int tid = threadIdx.x;

  const float* kg = kbuf + c * 68644 + h0 * 262;
  const float* vg = vbuf + c * 68644 + h0 * 262;
  #pragma unroll
  for (int r = 0; r < 10; ++r) {
    for (int col = tid; col < 262; col += 256) {
      ks[r * 264 + col] = kg[r * 262 + col];
      vs[r * 264 + col] = vg[r * 262 + col];
    }
  }
  #pragma unroll
  for (int r = 0; r < 4; ++r)
    qs[r * 256 + tid] = qbuf[c * 65536 + (h0 + r) * 256 + tid];
  if (tid < 7) {
    float s = 0.f;
    for (int cc = 0; cc < 16; ++cc) s += relh[cc * 7 + tid];
    rhs[tid] = s;
  } else if (tid >= 8 && tid < 15) {
    int j = tid - 8;
    float s = 0.f;
    for (int cc = 0; cc < 16; ++cc) s += relw[cc * 7 + j];
    rws[j] = s;
  }
  __syncthreads();

  int me = tid & 63, ty = tid >> 6;
  int h = h0 + ty;
  float4 qv4 = *(const float4*)&qs[ty * 256 + me * 4];
  float qv0 = qv4.x, qv1 = qv4.y, qv2 = qv4.z, qv3 = qv4.w;
  float qsum = qv0 + qv1 + qv2 + qv3;

  float qk[49];
  #pragma unroll
  for (int i = 0; i < 7; ++i) {
    const float* krow = &ks[(ty + i) * 264 + me * 4];
    float kwin[12];
    *(float4*)&kwin[0] = *(const float4*)&krow[0];
    *(float4*)&kwin[4] = *(const float4*)&krow[4];
    *(float4*)&kwin[8] = *(const float4*)&krow[8];
    float rh = rhs[i];
    #pragma unroll
    for (int j = 0; j < 7; ++j) {
      float d0 = fmaf(qv0, kwin[j],
                 fmaf(qv1, kwin[j + 1],
                 fmaf(qv2, kwin[j + 2], qv3 * kwin[j + 3])));
      qk[i * 7 + j] = fmaf(qsum, rh + rws[j], d0);
    }
  }
  float m = qk[0];
  #pragma unroll
  for (int z = 1; z < 49; ++z) m = fmaxf(m, qk[z]);
  float sum = 0.f;
  #pragma unroll
  for (int z = 0; z < 49; ++z) {
    float e = __expf(qk[z] - m);
    qk[z] = e;
    sum += e;
  }
  float inv = 1.0f / sum;

  float o0 = 0.f, o1 = 0.f, o2 = 0.f, o3 = 0.f;
  #pragma unroll
  for (int i = 0; i < 7; ++i) {
    const float* vrow = &vs[(ty + i) * 264 + me * 4];
    float vwin[12];
    *(float4*)&vwin[0] = *(const float4*)&vrow[0];
    *(float4*)&vwin[4] = *(const float4*)&vrow[4];
    *(float4*)&vwin[8] = *(const float4*)&vrow[8];
    #pragma unroll
    for (int j = 0; j < 7; ++j) {
      float p = qk[i * 7 + j];
      o0 = fmaf(p, vwin[j],     o0);
      o1 = fmaf(p, vwin[j + 1], o1);
      o2 = fmaf(p, vwin[j + 2], o2);
      o3 = fmaf(p, vwin[j + 3], o3);
    }
  }
  float4 out4 = make_float4(o0 * inv, o1 * inv, o2 * inv, o3 * inv);
  *(float4*)&att[c * 65536 + h * 256 + me * 4] = out4;
}

// K3: 342 linear-collapse sums; resize folded in (scatter form).
//  b<32 : thread at sc pos (iy,ix) computes the exact 2x2 average from att,
//         scatters into the <=9 (ky,kx) accumulators with valid out pos.
//  b>=32: Sx[b-32][ky][kx] = sum over out pos of x[ci, 8oy-1+ky, 8ox-1+kx]
__global__ __launch_bounds__(256) void k_sums(
    const float* __restrict__ x, const float* __restrict__ att,
    float* __restrict__ S) {
  int b = blockIdx.x, tid = threadIdx.x;
  float acc[9] = {0.f,0.f,0.f,0.f,0.f,0.f,0.f,0.f,0.f};
  if (b < 32) {
    const float* a = att + b * 65536;
    for (int p = tid; p < 1024; p += 256) {
      int iy = p >> 5, ix = p & 31;
      int y0 = 8 * iy + 3, x0 = 8 * ix + 3;
      float scv = 0.25f * (a[y0 * 256 + x0] + a[y0 * 256 + x0 + 1] +
                           a[(y0 + 1) * 256 + x0] + a[(y0 + 1) * 256 + x0 + 1]);
      #pragma unroll
      for (int ky = 0; ky < 3; ++ky) {
        int oy = iy - ky + 1;
        if (oy < 0 || oy > 31) continue;
        #pragma unroll
        for (int kx = 0; kx < 3; ++kx) {
          int ox = ix - kx + 1;
          if (ox < 0 || ox > 31) continue;
          acc[ky * 3 + kx] += scv;
        }
      }
    }
  } else {
    const float* xc = x + (size_t)(b - 32) * 65536;
    for (int p = tid; p < 1024; p += 256) {
      int oy = p >> 5, ox = p & 31;
      #pragma unroll
      for (int ky = 0; ky < 3; ++ky) {
        int iy = 8 * oy - 1 + ky;
        if (iy < 0 || iy > 255) continue;
        #pragma unroll
        for (int kx = 0; kx < 3; ++kx) {
          int ix = 8 * ox - 1 + kx;
          if (ix < 0 || ix > 255) continue;
          acc[ky * 3 + kx] += xc[iy * 256 + ix];
        }
      }
    }
  }
  __shared__ float part[4][9];
  #pragma unroll
  for (int k = 0; k < 9; ++k) {
    #pragma unroll
    for (int off = 32; off >= 1; off >>= 1)
      acc[k] += __shfl_down(acc[k], off);
  }
  int wave = tid >> 6, lane = tid & 63;
  if (lane == 0) {
    #pragma unroll
    for (int k = 0; k < 9; ++k) part[wave][k] = acc[k];
  }
  __syncthreads();
  if (tid < 9)
    S[b * 9 + tid] = part[0][tid] + part[1][tid] + part[2][tid] + part[3][tid];
}

// K4: pooled[oc] = bb+eb + (ew[oc,:].S[0:288] + bw[oc,:].S[288:342])/1024
// One block (64 lanes) per output channel: coalesced weight loads + shuffle.
__global__ __launch_bounds__(64) void k_pool(
    const float* __restrict__ S,
    const float* __restrict__ bw, const float* __restrict__ bb,
    const float* __restrict__ ew, const float* __restrict__ eb,
    float* __restrict__ pooled) {
  int oc = blockIdx.x, lane = threadIdx.x;
  float acc = 0.f;
  #pragma unroll
  for (int i0 = 0; i0 < 288; i0 += 64) {
    int i = i0 + lane;
    if (i < 288) acc = fmaf(ew[oc * 288 + i], S[i], acc);
  }
  if (lane < 54) acc = fmaf(bw[oc * 54 + lane], S[288 + lane], acc);
  #pragma unroll
  for (int off = 32; off >= 1; off >>= 1) acc += __shfl_down(acc, off);
  if (lane == 0)
    pooled[oc] = bb[oc] + eb[oc] + acc * (1.0f / 1024.0f);
}

// K5: fc head, one block (64 lanes) per class.
__global__ __launch_bounds__(64) void k_fc(
    const float* __restrict__ pooled, const float* __restrict__ fcw,
    const float* __restrict__ fcb, float* __restrict__ out) {
  int o = blockIdx.x, lane = threadIdx.x;
  float acc = 0.f;
  #pragma unroll
  for (int i0 = 0; i0 < 512; i0 += 64)
    acc = fmaf(fcw[o * 512 + i0 + lane], pooled[i0 + lane], acc);
  #pragma unroll
  for (int off = 32; off >= 1; off >>= 1) acc += __shfl_down(acc, off);
  if (lane == 0) out[o] = fcb[o] + acc;
}

extern "C" void kernel_launch(void* const* d_in, const int* in_sizes, int n_in,
                              void* d_out, int out_size, void* d_ws, size_t ws_size,
                              hipStream_t stream) {
  const float* x    = (const float*)d_in[0];
  // d_in[1] = diff_input (int, always 1) -> attention branch always taken
  const float* bw   = (const float*)d_in[2];
  const float* bb   = (const float*)d_in[3];
  const float* c1w  = (const float*)d_in[4];
  const float* c1b  = (const float*)d_in[5];
  const float* kw   = (const float*)d_in[6];
  const float* kb   = (const float*)d_in[7];
  const float* qw   = (const float*)d_in[8];
  const float* qb   = (const float*)d_in[9];
  const float* vw   = (const float*)d_in[10];
  const float* vb   = (const float*)d_in[11];
  const float* relh = (const float*)d_in[12];
  const float* relw = (const float*)d_in[13];
  const float* ew   = (const float*)d_in[14];
  const float* eb   = (const float*)d_in[15];
  const float* fcw  = (const float*)d_in[16];
  const float* fcb  = (const float*)d_in[17];

  float* ws   = (float*)d_ws;
  float* qbuf = ws + OFF_Q;
  float* kbuf = ws + OFF_K;
  float* vbuf = ws + OFF_V;
  float* att  = ws + OFF_ATT;
  float* Sbuf = ws + OFF_S;
  float* pool = ws + OFF_P;
  float* out  = (float*)d_out;

  k_front<<<269,  256, 0, stream>>>(x, c1w, c1b, kw, kb, qw, qb, vw, vb,
                                    kbuf, qbuf, vbuf);
  k_attn <<<2048, 256, 0, stream>>>(kbuf, qbuf, vbuf, relh, relw, att);
  k_sums <<<38,   256, 0, stream>>>(x, att, Sbuf);
  k_pool <<<512,  64,  0, stream>>>(Sbuf, bw, bb, ew, eb, pool);
  k_fc   <<<20,   64,  0, stream>>>(pool, fcw, fcb, out);
}

// Round 3
// 85.939 us; speedup vs baseline: 1.9116x; 1.3957x over previous
//
#include <hip/hip_runtime.h>
#include <math.h>

// ---------------------------------------------------------------------------
// CAM_Net fused pipeline, MI355X (gfx950) — round 3
//
// ws layout (floats):
//   q    [32][256][256]
//   k    [32][262][262]
//   v    [32][262][262]
//   att  [32][256][256]
//   S    [342]
//   pooled [512]
//   M    [96][54]   folded weight (W3 @ c1w), rows: 0-31 k, 32-63 q, 64-95 v
//   Mb   [96]       folded bias
//
// Algebra: conv1(3x3) then 1x1 conv == one 96x54 transform on the 6x3x3
// input patch. conv1/x1 never materialized. Backbone/expand convs collapse
// into 342 sums + 512x342 dot (k_sums/k_pool/k_fc). Bilinear 256->32 is an
// exact 2x2 average folded into k_sums.
// ---------------------------------------------------------------------------

#define OFF_Q   ((size_t)0)
#define OFF_K   ((size_t)2097152)
#define OFF_V   ((size_t)4293760)
#define OFF_ATT ((size_t)6490368)
#define OFF_S   ((size_t)8587520)
#define OFF_P   ((size_t)8587904)
#define OFF_M   ((size_t)8588416)
#define OFF_MB  ((size_t)8593600)
// total ~8.59M floats ~= 34.4 MB

// K0: fold weights. M[o][t] = sum_m W3[o][m]*c1w[m*54+t]; Mb[o]=b3[o]+W3[o,:].c1b
// 96 blocks x 64 threads, tiny.
__global__ __launch_bounds__(64) void k_wfold(
    const float* __restrict__ c1w, const float* __restrict__ c1b,
    const float* __restrict__ kw, const float* __restrict__ kb,
    const float* __restrict__ qw, const float* __restrict__ qb,
    const float* __restrict__ vw, const float* __restrict__ vb,
    float* __restrict__ M, float* __restrict__ Mb) {
  int o = blockIdx.x, t = threadIdx.x;
  const float* w3; float bias;
  if (o < 32)      { w3 = kw + o * 32;        bias = kb[o]; }
  else if (o < 64) { w3 = qw + (o - 32) * 32; bias = qb[o - 32]; }
  else             { w3 = vw + (o - 64) * 32; bias = vb[o - 64]; }
  if (t < 54) {
    float s = 0.f;
    #pragma unroll
    for (int m = 0; m < 32; ++m) s = fmaf(w3[m], c1w[m * 54 + t], s);
    M[o * 54 + t] = s;
  } else if (t == 63) {
    float s = bias;
    #pragma unroll
    for (int m = 0; m < 32; ++m) s = fmaf(w3[m], c1b[m], s);
    Mb[o] = s;
  }
}

// K1: per-pixel 54->96 transform. Block-uniform group g = blockIdx.x/269
// (12 groups of 8 out-channels: 0-3 k, 4-7 q, 8-11 v) -> weight reads are
// scalar (s_load). Thread p gathers its 6x3x3 patch from x (L2-resident).
__global__ __launch_bounds__(256) void k_front(
    const float* __restrict__ x,
    const float* __restrict__ M, const float* __restrict__ Mb,
    float* __restrict__ kbuf, float* __restrict__ qbuf, float* __restrict__ vbuf) {
  int g = blockIdx.x / 269;                    // 0..11, block-uniform
  int p = (blockIdx.x - g * 269) * 256 + threadIdx.x;
  if (p >= 68644) return;                      // 262*262
  unsigned py = (unsigned)p / 262u;
  unsigned px = (unsigned)p - py * 262u;
  bool interior = (py >= 3u && py < 259u && px >= 3u && px < 259u);
  int row0 = g * 8;                            // first of 8 out-channels
  const float* Mg = M + row0 * 54;

  if (!interior) {                             // x1 zero-pad -> bias only
    if (g < 4) {
      #pragma unroll
      for (int c = 0; c < 8; ++c) kbuf[(row0 + c) * 68644 + p] = Mb[row0 + c];
    } else if (g >= 8) {
      #pragma unroll
      for (int c = 0; c < 8; ++c) vbuf[(row0 - 64 + c) * 68644 + p] = Mb[row0 + c];
    }
    return;
  }
  int iy = (int)py - 3, ix = (int)px - 3;

  float acc[8];
  #pragma unroll
  for (int c = 0; c < 8; ++c) acc[c] = Mb[row0 + c];

  #pragma unroll
  for (int ci = 0; ci < 6; ++ci) {
    float patch[9];
    #pragma unroll
    for (int dy = 0; dy < 3; ++dy) {
      int yy = iy - 1 + dy;
      bool yok = (yy >= 0 && yy <= 255);
      #pragma unroll
      for (int dx = 0; dx < 3; ++dx) {
        int xx2 = ix - 1 + dx;
        bool ok = yok && (xx2 >= 0 && xx2 <= 255);
        patch[dy * 3 + dx] = ok ? x[ci * 65536 + yy * 256 + xx2] : 0.0f;
      }
    }
    #pragma unroll
    for (int c = 0; c < 8; ++c) {
      const float* wc = Mg + c * 54 + ci * 9;
      float s = acc[c];
      #pragma unroll
      for (int t = 0; t < 9; ++t) s = fmaf(wc[t], patch[t], s);
      acc[c] = s;
    }
  }

  if (g < 4) {
    #pragma unroll
    for (int c = 0; c < 8; ++c) kbuf[(row0 + c) * 68644 + p] = acc[c];
  } else if (g < 8) {
    int qidx = iy * 256 + ix;
    #pragma unroll
    for (int c = 0; c < 8; ++c) qbuf[(row0 - 32 + c) * 65536 + qidx] = acc[c];
  } else {
    #pragma unroll
    for (int c = 0; c < 8; ++c) vbuf[(row0 - 64 + c) * 68644 + p] = acc[c];
  }
}

// K2: attention. Block = (channel c, 4 rows), 256 threads; thread handles
// softmax group (c, h, w_base=4*(tid&63)). LDS rows padded to 264 floats.
__global__ __launch_bounds__(256) void k_attn(
    const float* __restrict__ kbuf, const float* __restrict__ qbuf,
    const float* __restrict__ vbuf, const float* __restrict__ relh,
    const float* __restrict__ relw, float* __restrict__ att) {
  __shared__ float ks[10 * 264];
  __shared__ float vs[10 * 264];
  __shared__ float qs[4 * 256];
  __shared__ float rhs[7];
  __shared__ float rws[7];
  int c  = blockIdx.x >> 6;
  int h0 = (blockIdx.x & 63) << 2;
  int tid = threadIdx.x;

  const float* kg = kbuf + c * 68644 + h0 * 262;
  const float* vg = vbuf + c * 68644 + h0 * 262;
  #pragma unroll
  for (int r = 0; r < 10; ++r) {
    for (int col = tid; col < 262; col += 256) {
      ks[r * 264 + col] = kg[r * 262 + col];
      vs[r * 264 + col] = vg[r * 262 + col];
    }
  }
  #pragma unroll
  for (int r = 0; r < 4; ++r)
    qs[r * 256 + tid] = qbuf[c * 65536 + (h0 + r) * 256 + tid];
  if (tid < 7) {
    float s = 0.f;
    for (int cc = 0; cc < 16; ++cc) s += relh[cc * 7 + tid];
    rhs[tid] = s;
  } else if (tid >= 8 && tid < 15) {
    int j = tid - 8;
    float s = 0.f;
    for (int cc = 0; cc < 16; ++cc) s += relw[cc * 7 + j];
    rws[j] = s;
  }
  __syncthreads();

  int me = tid & 63, ty = tid >> 6;
  int h = h0 + ty;
  float4 qv4 = *(const float4*)&qs[ty * 256 + me * 4];
  float qv0 = qv4.x, qv1 = qv4.y, qv2 = qv4.z, qv3 = qv4.w;
  float qsum = qv0 + qv1 + qv2 + qv3;

  float qk[49];
  #pragma unroll
  for (int i = 0; i < 7; ++i) {
    const float* krow = &ks[(ty + i) * 264 + me * 4];
    float kwin[12];
    *(float4*)&kwin[0] = *(const float4*)&krow[0];
    *(float4*)&kwin[4] = *(const float4*)&krow[4];
    *(float4*)&kwin[8] = *(const float4*)&krow[8];
    float rh = rhs[i];
    #pragma unroll
    for (int j = 0; j < 7; ++j) {
      float d0 = fmaf(qv0, kwin[j],
                 fmaf(qv1, kwin[j + 1],
                 fmaf(qv2, kwin[j + 2], qv3 * kwin[j + 3])));
      qk[i * 7 + j] = fmaf(qsum, rh + rws[j], d0);
    }
  }
  float m = qk[0];
  #pragma unroll
  for (int z = 1; z < 49; ++z) m = fmaxf(m, qk[z]);
  float sum = 0.f;
  #pragma unroll
  for (int z = 0; z < 49; ++z) {
    float e = __expf(qk[z] - m);
    qk[z] = e;
    sum += e;
  }
  float inv = 1.0f / sum;

  float o0 = 0.f, o1 = 0.f, o2 = 0.f, o3 = 0.f;
  #pragma unroll
  for (int i = 0; i < 7; ++i) {
    const float* vrow = &vs[(ty + i) * 264 + me * 4];
    float vwin[12];
    *(float4*)&vwin[0] = *(const float4*)&vrow[0];
    *(float4*)&vwin[4] = *(const float4*)&vrow[4];
    *(float4*)&vwin[8] = *(const float4*)&vrow[8];
    #pragma unroll
    for (int j = 0; j < 7; ++j) {
      float p = qk[i * 7 + j];
      o0 = fmaf(p, vwin[j],     o0);
      o1 = fmaf(p, vwin[j + 1], o1);
      o2 = fmaf(p, vwin[j + 2], o2);
      o3 = fmaf(p, vwin[j + 3], o3);
    }
  }
  float4 out4 = make_float4(o0 * inv, o1 * inv, o2 * inv, o3 * inv);
  *(float4*)&att[c * 65536 + h * 256 + me * 4] = out4;
}

// K3: 342 linear-collapse sums; resize folded in (scatter form).
__global__ __launch_bounds__(256) void k_sums(
    const float* __restrict__ x, const float* __restrict__ att,
    float* __restrict__ S) {
  int b = blockIdx.x, tid = threadIdx.x;
  float acc[9] = {0.f,0.f,0.f,0.f,0.f,0.f,0.f,0.f,0.f};
  if (b < 32) {
    const float* a = att + b * 65536;
    for (int p = tid; p < 1024; p += 256) {
      int iy = p >> 5, ix = p & 31;
      int y0 = 8 * iy + 3, x0 = 8 * ix + 3;
      float scv = 0.25f * (a[y0 * 256 + x0] + a[y0 * 256 + x0 + 1] +
                           a[(y0 + 1) * 256 + x0] + a[(y0 + 1) * 256 + x0 + 1]);
      #pragma unroll
      for (int ky = 0; ky < 3; ++ky) {
        int oy = iy - ky + 1;
        if (oy < 0 || oy > 31) continue;
        #pragma unroll
        for (int kx = 0; kx < 3; ++kx) {
          int ox = ix - kx + 1;
          if (ox < 0 || ox > 31) continue;
          acc[ky * 3 + kx] += scv;
        }
      }
    }
  } else {
    const float* xc = x + (size_t)(b - 32) * 65536;
    for (int p = tid; p < 1024; p += 256) {
      int oy = p >> 5, ox = p & 31;
      #pragma unroll
      for (int ky = 0; ky < 3; ++ky) {
        int iy = 8 * oy - 1 + ky;
        if (iy < 0 || iy > 255) continue;
        #pragma unroll
        for (int kx = 0; kx < 3; ++kx) {
          int ix = 8 * ox - 1 + kx;
          if (ix < 0 || ix > 255) continue;
          acc[ky * 3 + kx] += xc[iy * 256 + ix];
        }
      }
    }
  }
  __shared__ float part[4][9];
  #pragma unroll
  for (int k = 0; k < 9; ++k) {
    #pragma unroll
    for (int off = 32; off >= 1; off >>= 1)
      acc[k] += __shfl_down(acc[k], off);
  }
  int wave = tid >> 6, lane = tid & 63;
  if (lane == 0) {
    #pragma unroll
    for (int k = 0; k < 9; ++k) part[wave][k] = acc[k];
  }
  __syncthreads();
  if (tid < 9)
    S[b * 9 + tid] = part[0][tid] + part[1][tid] + part[2][tid] + part[3][tid];
}

// K4: pooled[oc] = bb+eb + (ew[oc,:].S[0:288] + bw[oc,:].S[288:342])/1024
__global__ __launch_bounds__(64) void k_pool(
    const float* __restrict__ S,
    const float* __restrict__ bw, const float* __restrict__ bb,
    const float* __restrict__ ew, const float* __restrict__ eb,
    float* __restrict__ pooled) {
  int oc = blockIdx.x, lane = threadIdx.x;
  float acc = 0.f;
  #pragma unroll
  for (int i0 = 0; i0 < 288; i0 += 64) {
    int i = i0 + lane;
    if (i < 288) acc = fmaf(ew[oc * 288 + i], S[i], acc);
  }
  if (lane < 54) acc = fmaf(bw[oc * 54 + lane], S[288 + lane], acc);
  #pragma unroll
  for (int off = 32; off >= 1; off >>= 1) acc += __shfl_down(acc, off);
  if (lane == 0)
    pooled[oc] = bb[oc] + eb[oc] + acc * (1.0f / 1024.0f);
}

// K5: fc head, one block (64 lanes) per class.
__global__ __launch_bounds__(64) void k_fc(
    const float* __restrict__ pooled, const float* __restrict__ fcw,
    const float* __restrict__ fcb, float* __restrict__ out) {
  int o = blockIdx.x, lane = threadIdx.x;
  float acc = 0.f;
  #pragma unroll
  for (int i0 = 0; i0 < 512; i0 += 64)
    acc = fmaf(fcw[o * 512 + i0 + lane], pooled[i0 + lane], acc);
  #pragma unroll
  for (int off = 32; off >= 1; off >>= 1) acc += __shfl_down(acc, off);
  if (lane == 0) out[o] = fcb[o] + acc;
}

extern "C" void kernel_launch(void* const* d_in, const int* in_sizes, int n_in,
                              void* d_out, int out_size, void* d_ws, size_t ws_size,
                              hipStream_t stream) {
  const float* x    = (const float*)d_in[0];
  // d_in[1] = diff_input (int, always 1) -> attention branch always taken
  const float* bw   = (const float*)d_in[2];
  const float* bb   = (const float*)d_in[3];
  const float* c1w  = (const float*)d_in[4];
  const float* c1b  = (const float*)d_in[5];
  const float* kw   = (const float*)d_in[6];
  const float* kb   = (const float*)d_in[7];
  const float* qw   = (const float*)d_in[8];
  const float* qb   = (const float*)d_in[9];
  const float* vw   = (const float*)d_in[10];
  const float* vb   = (const float*)d_in[11];
  const float* relh = (const float*)d_in[12];
  const float* relw = (const float*)d_in[13];
  const float* ew   = (const float*)d_in[14];
  const float* eb   = (const float*)d_in[15];
  const float* fcw  = (const float*)d_in[16];
  const float* fcb  = (const float*)d_in[17];

  float* ws   = (float*)d_ws;
  float* qbuf = ws + OFF_Q;
  float* kbuf = ws + OFF_K;
  float* vbuf = ws + OFF_V;
  float* att  = ws + OFF_ATT;
  float* Sbuf = ws + OFF_S;
  float* pool = ws + OFF_P;
  float* Mbuf = ws + OFF_M;
  float* Mb   = ws + OFF_MB;
  float* out  = (float*)d_out;

  k_wfold<<<96,   64,  0, stream>>>(c1w, c1b, kw, kb, qw, qb, vw, vb, Mbuf, Mb);
  k_front<<<3228, 256, 0, stream>>>(x, Mbuf, Mb, kbuf, qbuf, vbuf);
  k_attn <<<2048, 256, 0, stream>>>(kbuf, qbuf, vbuf, relh, relw, att);
  k_sums <<<38,   256, 0, stream>>>(x, att, Sbuf);
  k_pool <<<512,  64,  0, stream>>>(Sbuf, bw, bb, ew, eb, pool);
  k_fc   <<<20,   64,  0, stream>>>(pool, fcw, fcb, out);
}

// Round 4
// 59.580 us; speedup vs baseline: 2.7573x; 1.4424x over previous
//
#include <hip/hip_runtime.h>
#include <math.h>

// ---------------------------------------------------------------------------
// CAM_Net fused pipeline, MI355X (gfx950) — round 4
//
// Key algebra this round:
//  * att_res is consumed ONLY via bilinear 256->32 (exact 2x2 avg at rows/cols
//    == 3,4 mod 8). So attention is computed at 1/16 of pixels only.
//  * The 3x3-window sums over the 32x32 resized map are RECTANGLE sums:
//    S[c][ky][kx] = T - exRow - exCol + corner, from 9 scalars per channel.
//    k_attn reduces its values straight to per-block partials; att/sc never
//    materialize. No atomics -> bit-deterministic.
//  * conv1+1x1 fold (M = W3@C1, 96x54); backbone/expand collapse to 342 sums.
//
// ws layout (floats):
//   q      [32][256][256]  (only rows ==3,4 mod 8 are written/read)
//   k      [32][262][262]
//   v      [32][262][262]
//   statA  [32][16][3]     per (c, row-pair block): {T, col0, col31} partials
//   statB  [32][6]         {r0, r31, e00, e0_31, e31_0, e31_31} direct-owned
//   Sx     [54]            x-side strided window sums (6ch x 9)
//   M      [96][54], Mb[96]
//   pooled [512]
// ---------------------------------------------------------------------------

#define OFF_Q     ((size_t)0)
#define OFF_K     ((size_t)2097152)
#define OFF_V     ((size_t)4293760)
#define OFF_STATA ((size_t)6490368)
#define OFF_STATB ((size_t)6491904)
#define OFF_SX    ((size_t)6492096)
#define OFF_M     ((size_t)6492160)
#define OFF_MB    ((size_t)6497344)
#define OFF_P     ((size_t)6497440)
// total ~6.50M floats ~= 26 MB

// K0: blocks 0..95 fold M/Mb; blocks 96..149 x-side strided sums -> Sx[54].
__global__ __launch_bounds__(256) void k_prep(
    const float* __restrict__ x,
    const float* __restrict__ c1w, const float* __restrict__ c1b,
    const float* __restrict__ kw, const float* __restrict__ kb,
    const float* __restrict__ qw, const float* __restrict__ qb,
    const float* __restrict__ vw, const float* __restrict__ vb,
    float* __restrict__ M, float* __restrict__ Mb, float* __restrict__ Sx) {
  int b = blockIdx.x, t = threadIdx.x;
  if (b < 96) {
    const float* w3; float bias;
    if (b < 32)      { w3 = kw + b * 32;        bias = kb[b]; }
    else if (b < 64) { w3 = qw + (b - 32) * 32; bias = qb[b - 32]; }
    else             { w3 = vw + (b - 64) * 32; bias = vb[b - 64]; }
    if (t < 54) {
      float s = 0.f;
      #pragma unroll
      for (int m = 0; m < 32; ++m) s = fmaf(w3[m], c1w[m * 54 + t], s);
      M[b * 54 + t] = s;
    } else if (t == 63) {
      float s = bias;
      #pragma unroll
      for (int m = 0; m < 32; ++m) s = fmaf(w3[m], c1b[m], s);
      Mb[b] = s;
    }
    return;
  }
  // x sums: Sx[ci][ky][kx] = sum over (oy,ox) of x[ci][8oy-1+ky][8ox-1+kx]
  int e = b - 96;                  // 0..53
  int ci = e / 9, rem = e - ci * 9, ky = rem / 3, kx = rem - ky * 3;
  const float* xc = x + (size_t)ci * 65536;
  float acc = 0.f;
  for (int p = t; p < 1024; p += 256) {
    int oy = p >> 5, ox = p & 31;
    int ry = 8 * oy - 1 + ky, cx = 8 * ox - 1 + kx;
    if (ry >= 0 && ry <= 255 && cx >= 0 && cx <= 255)
      acc += xc[ry * 256 + cx];
  }
  #pragma unroll
  for (int off = 32; off >= 1; off >>= 1) acc += __shfl_down(acc, off);
  __shared__ float part[4];
  if ((t & 63) == 0) part[t >> 6] = acc;
  __syncthreads();
  if (t == 0) Sx[e] = part[0] + part[1] + part[2] + part[3];
}

// K1: per-pixel 54->96 transform (12 groups of 8 out-channels; 0-3 k, 4-7 q,
// 8-11 v). q computed only at rows ==3,4 mod 8 (the only rows attention reads).
__global__ __launch_bounds__(256) void k_front(
    const float* __restrict__ x,
    const float* __restrict__ M, const float* __restrict__ Mb,
    float* __restrict__ kbuf, float* __restrict__ qbuf, float* __restrict__ vbuf) {
  int g = blockIdx.x / 269;                    // 0..11, block-uniform
  int p = (blockIdx.x - g * 269) * 256 + threadIdx.x;
  if (p >= 68644) return;                      // 262*262
  unsigned py = (unsigned)p / 262u;
  unsigned px = (unsigned)p - py * 262u;
  bool interior = (py >= 3u && py < 259u && px >= 3u && px < 259u);
  int row0 = g * 8;
  const float* Mg = M + row0 * 54;

  if (!interior) {                             // x1 zero-pad -> bias only
    if (g < 4) {
      #pragma unroll
      for (int c = 0; c < 8; ++c) kbuf[(row0 + c) * 68644 + p] = Mb[row0 + c];
    } else if (g >= 8) {
      #pragma unroll
      for (int c = 0; c < 8; ++c) vbuf[(row0 - 64 + c) * 68644 + p] = Mb[row0 + c];
    }
    return;
  }
  int iy = (int)py - 3, ix = (int)px - 3;
  bool isq = (g >= 4 && g < 8);
  if (isq && ((iy & 7) != 3 && (iy & 7) != 4)) return;   // unread q rows

  float acc[8];
  #pragma unroll
  for (int c = 0; c < 8; ++c) acc[c] = Mb[row0 + c];

  #pragma unroll
  for (int ci = 0; ci < 6; ++ci) {
    float patch[9];
    #pragma unroll
    for (int dy = 0; dy < 3; ++dy) {
      int yy = iy - 1 + dy;
      bool yok = (yy >= 0 && yy <= 255);
      #pragma unroll
      for (int dx = 0; dx < 3; ++dx) {
        int xx2 = ix - 1 + dx;
        bool ok = yok && (xx2 >= 0 && xx2 <= 255);
        patch[dy * 3 + dx] = ok ? x[ci * 65536 + yy * 256 + xx2] : 0.0f;
      }
    }
    #pragma unroll
    for (int c = 0; c < 8; ++c) {
      const float* wc = Mg + c * 54 + ci * 9;
      float s = acc[c];
      #pragma unroll
      for (int t = 0; t < 9; ++t) s = fmaf(wc[t], patch[t], s);
      acc[c] = s;
    }
  }

  if (g < 4) {
    #pragma unroll
    for (int c = 0; c < 8; ++c) kbuf[(row0 + c) * 68644 + p] = acc[c];
  } else if (isq) {
    int qidx = iy * 256 + ix;
    #pragma unroll
    for (int c = 0; c < 8; ++c) qbuf[(row0 - 32 + c) * 65536 + qidx] = acc[c];
  } else {
    #pragma unroll
    for (int c = 0; c < 8; ++c) vbuf[(row0 - 64 + c) * 68644 + p] = acc[c];
  }
}

// K2: attention at needed pixels only + reduction to rect-sum stats.
// Block = (c, b16): output rows oy0=2*b16, oy0+1. Thread tid:
//   ox=tid&31, dy=(tid>>5)&1, dx=(tid>>6)&1, oyl=(tid>>7)&1
//   pixel (h = 8*(oy0+oyl)+3+dy, w = 8*ox+3+dx); group wb=8*ox+4*dx, d=3-3*dx.
__global__ __launch_bounds__(256) void k_attn(
    const float* __restrict__ kbuf, const float* __restrict__ qbuf,
    const float* __restrict__ vbuf, const float* __restrict__ relh,
    const float* __restrict__ relw,
    float* __restrict__ statA, float* __restrict__ statB) {
  __shared__ float ks[16 * 264];
  __shared__ float vs[16 * 264];
  __shared__ float qs[4 * 256];
  __shared__ float rhs[7];
  __shared__ float rws[7];
  __shared__ float red[256];
  __shared__ float grp[2][3];                  // per-oyl {rowsum, e0, e31}

  int c   = blockIdx.x >> 4;
  int b16 = blockIdx.x & 15;
  int oy0 = 2 * b16;
  int pr0 = 16 * b16 + 3;                      // first padded k/v row
  int tid = threadIdx.x;

  const float* kg = kbuf + c * 68644;
  const float* vg = vbuf + c * 68644;
  #pragma unroll
  for (int r = 0; r < 16; ++r) {
    for (int col = tid; col < 262; col += 256) {
      ks[r * 264 + col] = kg[(pr0 + r) * 262 + col];
      vs[r * 264 + col] = vg[(pr0 + r) * 262 + col];
    }
  }
  {
    const int qrows[4] = {3, 4, 11, 12};
    #pragma unroll
    for (int r = 0; r < 4; ++r)
      qs[r * 256 + tid] = qbuf[c * 65536 + (8 * oy0 + qrows[r]) * 256 + tid];
  }
  if (tid < 7) {
    float s = 0.f;
    for (int cc = 0; cc < 16; ++cc) s += relh[cc * 7 + tid];
    rhs[tid] = s;
  } else if (tid >= 8 && tid < 15) {
    int j = tid - 8;
    float s = 0.f;
    for (int cc = 0; cc < 16; ++cc) s += relw[cc * 7 + j];
    rws[j] = s;
  }
  __syncthreads();

  int ox  = tid & 31;
  int dy  = (tid >> 5) & 1;
  int dx  = (tid >> 6) & 1;
  int oyl = (tid >> 7) & 1;
  int wb  = 8 * ox + 4 * dx;
  int d   = dx ? 0 : 3;
  int lrow0 = 8 * oyl + dy;
  int qrow  = oyl * 2 + dy;

  float4 qv4 = *(const float4*)&qs[qrow * 256 + wb];
  float qv0 = qv4.x, qv1 = qv4.y, qv2 = qv4.z, qv3 = qv4.w;
  float qsum = qv0 + qv1 + qv2 + qv3;

  float qk[49];
  #pragma unroll
  for (int i = 0; i < 7; ++i) {
    const float* krow = &ks[(lrow0 + i) * 264 + wb];
    float kwin[12];
    *(float4*)&kwin[0] = *(const float4*)&krow[0];
    *(float4*)&kwin[4] = *(const float4*)&krow[4];
    *(float4*)&kwin[8] = *(const float4*)&krow[8];
    float rh = rhs[i];
    #pragma unroll
    for (int j = 0; j < 7; ++j) {
      float d0 = fmaf(qv0, kwin[j],
                 fmaf(qv1, kwin[j + 1],
                 fmaf(qv2, kwin[j + 2], qv3 * kwin[j + 3])));
      qk[i * 7 + j] = fmaf(qsum, rh + rws[j], d0);
    }
  }
  float m = qk[0];
  #pragma unroll
  for (int z = 1; z < 49; ++z) m = fmaxf(m, qk[z]);
  float sum = 0.f;
  #pragma unroll
  for (int z = 0; z < 49; ++z) {
    float e = __expf(qk[z] - m);
    qk[z] = e;
    sum += e;
  }
  float inv = 1.0f / sum;

  float o = 0.f;
  #pragma unroll
  for (int i = 0; i < 7; ++i) {
    const float* vrow = &vs[(lrow0 + i) * 264 + wb];
    float vwin[12];
    *(float4*)&vwin[0] = *(const float4*)&vrow[0];
    *(float4*)&vwin[4] = *(const float4*)&vrow[4];
    *(float4*)&vwin[8] = *(const float4*)&vrow[8];
    #pragma unroll
    for (int j = 0; j < 7; ++j)
      o = fmaf(qk[i * 7 + j], vwin[d + j], o);
  }
  float quarter = 0.25f * o * inv;             // this pixel's share of sc

  // combine dy (bit5, same wave), then dx (bit6, cross-wave via LDS)
  float pairsum = quarter + __shfl_xor(quarter, 32);
  red[tid] = pairsum;
  __syncthreads();

  if ((tid & 96) == 0) {                       // dy=0, dx=0 lanes: 2x32 threads
    float scv = red[tid] + red[tid ^ 64];      // sc[c][oy0+oyl][ox]
    float e31v = __shfl(scv, 31, 32);
    float e0v  = __shfl(scv, 0, 32);
    float rs = scv;
    #pragma unroll
    for (int off = 16; off >= 1; off >>= 1) rs += __shfl_down(rs, off, 32);
    if (ox == 0) {
      grp[oyl][0] = rs; grp[oyl][1] = e0v; grp[oyl][2] = e31v;
    }
  }
  __syncthreads();

  if (tid == 0) {
    float* pa = statA + (c * 16 + b16) * 3;
    pa[0] = grp[0][0] + grp[1][0];             // T partial
    pa[1] = grp[0][1] + grp[1][1];             // col0 partial
    pa[2] = grp[0][2] + grp[1][2];             // col31 partial
    if (b16 == 0) {                            // owns row 0
      statB[c * 6 + 0] = grp[0][0];            // r0
      statB[c * 6 + 2] = grp[0][1];            // e00
      statB[c * 6 + 3] = grp[0][2];            // e0_31
    }
    if (b16 == 15) {                           // owns row 31
      statB[c * 6 + 1] = grp[1][0];            // r31
      statB[c * 6 + 4] = grp[1][1];            // e31_0
      statB[c * 6 + 5] = grp[1][2];            // e31_31
    }
  }
}

// K3: pooled[oc]. Reconstruct S[342] from stats (rect-sum closed form) in LDS,
// then dot with [ew|bw] row oc. One 64-lane block per oc.
__global__ __launch_bounds__(64) void k_pool(
    const float* __restrict__ statA, const float* __restrict__ statB,
    const float* __restrict__ Sx,
    const float* __restrict__ bw, const float* __restrict__ bb,
    const float* __restrict__ ew, const float* __restrict__ eb,
    float* __restrict__ pooled) {
  __shared__ float Sl[342];
  int oc = blockIdx.x, lane = threadIdx.x;
  if (lane < 32) {
    int ch = lane;
    float T = 0.f, C0 = 0.f, C31 = 0.f;
    #pragma unroll
    for (int i = 0; i < 16; ++i) {
      const float* pa = statA + (ch * 16 + i) * 3;
      T += pa[0]; C0 += pa[1]; C31 += pa[2];
    }
    const float* pb = statB + ch * 6;
    float r0 = pb[0], r31 = pb[1];
    float e00 = pb[2], e0_31 = pb[3], e31_0 = pb[4], e31_31 = pb[5];
    #pragma unroll
    for (int ky = 0; ky < 3; ++ky) {
      float exR = (ky == 0) ? r31 : (ky == 2 ? r0 : 0.f);
      #pragma unroll
      for (int kx = 0; kx < 3; ++kx) {
        float exC = (kx == 0) ? C31 : (kx == 2 ? C0 : 0.f);
        float corner = 0.f;
        if (ky != 1 && kx != 1) {
          if (ky == 0) corner = (kx == 0) ? e31_31 : e31_0;
          else         corner = (kx == 0) ? e0_31  : e00;
        }
        Sl[ch * 9 + ky * 3 + kx] = T - exR - exC + corner;
      }
    }
  } else if (lane < 54 + 32 - 32) {
    // covered below
  }
  if (lane < 54) Sl[288 + lane] = Sx[lane];
  __syncthreads();

  float acc = 0.f;
  #pragma unroll
  for (int i0 = 0; i0 < 342; i0 += 64) {
    int i = i0 + lane;
    if (i < 342) {
      float wv = (i < 288) ? ew[oc * 288 + i] : bw[oc * 54 + (i - 288)];
      acc = fmaf(wv, Sl[i], acc);
    }
  }
  #pragma unroll
  for (int off = 32; off >= 1; off >>= 1) acc += __shfl_down(acc, off);
  if (lane == 0)
    pooled[oc] = bb[oc] + eb[oc] + acc * (1.0f / 1024.0f);
}

// K4: fc head, one block (64 lanes) per class.
__global__ __launch_bounds__(64) void k_fc(
    const float* __restrict__ pooled, const float* __restrict__ fcw,
    const float* __restrict__ fcb, float* __restrict__ out) {
  int o = blockIdx.x, lane = threadIdx.x;
  float acc = 0.f;
  #pragma unroll
  for (int i0 = 0; i0 < 512; i0 += 64)
    acc = fmaf(fcw[o * 512 + i0 + lane], pooled[i0 + lane], acc);
  #pragma unroll
  for (int off = 32; off >= 1; off >>= 1) acc += __shfl_down(acc, off);
  if (lane == 0) out[o] = fcb[o] + acc;
}

extern "C" void kernel_launch(void* const* d_in, const int* in_sizes, int n_in,
                              void* d_out, int out_size, void* d_ws, size_t ws_size,
                              hipStream_t stream) {
  const float* x    = (const float*)d_in[0];
  // d_in[1] = diff_input (int, always 1) -> attention branch always taken
  const float* bw   = (const float*)d_in[2];
  const float* bb   = (const float*)d_in[3];
  const float* c1w  = (const float*)d_in[4];
  const float* c1b  = (const float*)d_in[5];
  const float* kw   = (const float*)d_in[6];
  const float* kb   = (const float*)d_in[7];
  const float* qw   = (const float*)d_in[8];
  const float* qb   = (const float*)d_in[9];
  const float* vw   = (const float*)d_in[10];
  const float* vb   = (const float*)d_in[11];
  const float* relh = (const float*)d_in[12];
  const float* relw = (const float*)d_in[13];
  const float* ew   = (const float*)d_in[14];
  const float* eb   = (const float*)d_in[15];
  const float* fcw  = (const float*)d_in[16];
  const float* fcb  = (const float*)d_in[17];

  float* ws    = (float*)d_ws;
  float* qbuf  = ws + OFF_Q;
  float* kbuf  = ws + OFF_K;
  float* vbuf  = ws + OFF_V;
  float* statA = ws + OFF_STATA;
  float* statB = ws + OFF_STATB;
  float* Sxb   = ws + OFF_SX;
  float* Mbuf  = ws + OFF_M;
  float* Mb    = ws + OFF_MB;
  float* pool  = ws + OFF_P;
  float* out   = (float*)d_out;

  k_prep <<<150,  256, 0, stream>>>(x, c1w, c1b, kw, kb, qw, qb, vw, vb,
                                    Mbuf, Mb, Sxb);
  k_front<<<3228, 256, 0, stream>>>(x, Mbuf, Mb, kbuf, qbuf, vbuf);
  k_attn <<<512,  256, 0, stream>>>(kbuf, qbuf, vbuf, relh, relw, statA, statB);
  k_pool <<<512,  64,  0, stream>>>(statA, statB, Sxb, bw, bb, ew, eb, pool);
  k_fc   <<<20,   64,  0, stream>>>(pool, fcw, fcb, out);
}

// Round 5
// 50.351 us; speedup vs baseline: 3.2627x; 1.1833x over previous
//
#include <hip/hip_runtime.h>
#include <math.h>

// ---------------------------------------------------------------------------
// CAM_Net fused pipeline, MI355X (gfx950) — round 5
//
// THREE launches total:
//   k_fused (566 blocks): blocks 0..511 = (c, b16) attention tiles that
//     compute their own k/q/v from x via per-block folded weights (M = W3@C1),
//     run windowed softmax-attention at the 1/16 resize-sampled pixels only,
//     and reduce straight to rectangle-sum stats. Blocks 512..565 = x-side
//     strided window sums Sx[54].
//   k_pool (512): reconstruct S[342] from stats (rect-sum closed form),
//     dot with [expand|backbone] weight row -> pooled[512].
//   k_fc (20): 512-dot per class.
//
// No k/q/v global buffers, no att map, no resize buffer. ws = 2.3K floats.
// Determinism: no atomics; every ws/out element written every call.
//
// LDS (floats): xs[18*264] staging ALIASED with KT[16*268] (xs dead before
// KT writes); VT[16*268]; QS[4*256]; Ml[6*28]; bias[8]; rhs/rws; red[256].
// K/V tile layout: padded col pc stored at slot pc+1 (stride 268) so conv
// writes are aligned float4; attention reads 4 aligned chunks per row.
// ---------------------------------------------------------------------------

#define OFF_STATA ((size_t)0)
#define OFF_STATB ((size_t)1536)
#define OFF_SX    ((size_t)1728)
#define OFF_P     ((size_t)1792)
// total 2304 floats

#define SM_XS   0                  // 18*264 = 4752  (alias KT 16*268=4288)
#define SM_VT   4752               // 16*268 = 4288
#define SM_QS   (4752 + 4288)      // 1024
#define SM_ML   (SM_QS + 1024)     // 168
#define SM_BIAS (SM_ML + 168)      // 8
#define SM_RHS  (SM_BIAS + 8)      // 8
#define SM_RWS  (SM_RHS + 8)       // 8
#define SM_RED  (SM_RWS + 8)       // 256
#define SM_GRP  (SM_RED + 256)     // 8
#define SM_TOT  (SM_GRP + 8)       // 10520 floats = 42.1 KB

__global__ __launch_bounds__(256) void k_fused(
    const float* __restrict__ x,
    const float* __restrict__ c1w, const float* __restrict__ c1b,
    const float* __restrict__ kw, const float* __restrict__ kb,
    const float* __restrict__ qw, const float* __restrict__ qb,
    const float* __restrict__ vw, const float* __restrict__ vb,
    const float* __restrict__ relh, const float* __restrict__ relw,
    float* __restrict__ statA, float* __restrict__ statB,
    float* __restrict__ Sx) {
  __shared__ float smem[SM_TOT];
  int tid = threadIdx.x;

  // ---- Sx side-blocks -----------------------------------------------------
  if (blockIdx.x >= 512) {
    int e = blockIdx.x - 512;              // 0..53
    int ci = e / 9, rem = e - ci * 9, ky = rem / 3, kx = rem - ky * 3;
    const float* xc = x + (size_t)ci * 65536;
    float acc = 0.f;
    for (int p = tid; p < 1024; p += 256) {
      int oy = p >> 5, ox = p & 31;
      int ry = 8 * oy - 1 + ky, cx = 8 * ox - 1 + kx;
      if (ry >= 0 && ry <= 255 && cx >= 0 && cx <= 255)
        acc += xc[ry * 256 + cx];
    }
    #pragma unroll
    for (int off = 32; off >= 1; off >>= 1) acc += __shfl_down(acc, off);
    float* part = smem + SM_RED;
    if ((tid & 63) == 0) part[tid >> 6] = acc;
    __syncthreads();
    if (tid == 0) Sx[e] = part[0] + part[1] + part[2] + part[3];
    return;
  }

  // ---- main attention-tile blocks ----------------------------------------
  int c   = blockIdx.x >> 4;
  int b16 = blockIdx.x & 15;
  int r0  = b16 << 4;                      // x1 row base of tile

  float* xs   = smem + SM_XS;
  float* KT   = smem + SM_XS;              // alias (after conv)
  float* VT   = smem + SM_VT;
  float* QS   = smem + SM_QS;
  float* Ml   = smem + SM_ML;
  float* bsl  = smem + SM_BIAS;
  float* rhs  = smem + SM_RHS;
  float* rws  = smem + SM_RWS;
  float* red  = smem + SM_RED;
  float* grp  = smem + SM_GRP;

  // Phase 0: weight fold + misc + stage channel 0
  if (tid < 168) {
    int ci = tid / 28, s = tid - ci * 28;
    if (s < 27) {
      int kind = s / 9, t9 = s - kind * 9;
      const float* w3 = (kind == 0 ? kw : (kind == 1 ? vw : qw)) + c * 32;
      float a = 0.f;
      #pragma unroll
      for (int m = 0; m < 32; ++m)
        a = fmaf(w3[m], c1w[(m * 6 + ci) * 9 + t9], a);
      Ml[ci * 28 + s] = a;
    }
  } else if (tid < 176) {
    int s = tid - 168;
    if (s < 3) {
      const float* w3 = (s == 0 ? kw : (s == 1 ? vw : qw)) + c * 32;
      float a = (s == 0 ? kb : (s == 1 ? vb : qb))[c];
      #pragma unroll
      for (int m = 0; m < 32; ++m) a = fmaf(w3[m], c1b[m], a);
      bsl[s] = a;
    } else if (s == 3) bsl[3] = kb[c];
    else if (s == 4) bsl[4] = vb[c];
  } else if (tid < 184) {
    int i = tid - 176;
    if (i < 7) {
      float s = 0.f;
      for (int cc = 0; cc < 16; ++cc) s += relh[cc * 7 + i];
      rhs[i] = s;
    }
  } else if (tid < 192) {
    int j = tid - 184;
    if (j < 7) {
      float s = 0.f;
      for (int cc = 0; cc < 16; ++cc) s += relw[cc * 7 + j];
      rws[j] = s;
    }
  }
  // stage xs for channel 0: xs[sr][slot], x row r0-1+sr, x col slot-4
  for (int e = tid; e < 18 * 264; e += 256) {
    int sr = e / 264, slot = e - sr * 264;
    int xr = r0 - 1 + sr, xc = slot - 4;
    float v = 0.f;
    if ((unsigned)xr < 256u && (unsigned)xc < 256u)
      v = x[xr * 256 + xc];
    xs[e] = v;
  }
  __syncthreads();

  // conv accumulators: thread owns 4x4 x1 tile (rows 4rq.., cols 4tq..)
  int tq = tid & 63, rq = tid >> 6;
  int roq = (rq & 1) ? 0 : 3;              // q rows: rq0->3, rq1->0(4), rq2->3(11), rq3->0(12)
  float kacc[4][4], vacc[4][4], qacc[4];
  {
    float mk = bsl[0], mv = bsl[1], mq = bsl[2];
    #pragma unroll
    for (int ro = 0; ro < 4; ++ro)
      #pragma unroll
      for (int cc = 0; cc < 4; ++cc) { kacc[ro][cc] = mk; vacc[ro][cc] = mv; }
    #pragma unroll
    for (int cc = 0; cc < 4; ++cc) qacc[cc] = mq;
  }

  #pragma unroll 1
  for (int ci = 0; ci < 6; ++ci) {
    float wch[28];
    {
      const float4* Mc = (const float4*)&Ml[ci * 28];
      *(float4*)&wch[0]  = Mc[0];
      *(float4*)&wch[4]  = Mc[1];
      *(float4*)&wch[8]  = Mc[2];
      *(float4*)&wch[12] = Mc[3];
      *(float4*)&wch[16] = Mc[4];
      *(float4*)&wch[20] = Mc[5];
      *(float4*)&wch[24] = Mc[6];
    }
    #pragma unroll
    for (int sr6 = 0; sr6 < 6; ++sr6) {
      int sr = 4 * rq + sr6;
      float w[12];
      const float* xrow = &xs[sr * 264 + 4 * tq];
      *(float4*)&w[0] = *(const float4*)&xrow[0];
      *(float4*)&w[4] = *(const float4*)&xrow[4];
      *(float4*)&w[8] = *(const float4*)&xrow[8];
      #pragma unroll
      for (int ro = 0; ro < 4; ++ro) {
        int dy = sr6 - ro;
        if (dy < 0 || dy > 2) continue;
        const float* wk = &wch[3 * dy];
        const float* wv = &wch[9 + 3 * dy];
        const float* wq = &wch[18 + 3 * dy];
        #pragma unroll
        for (int cc = 0; cc < 4; ++cc) {
          float a = kacc[ro][cc], b2 = vacc[ro][cc];
          #pragma unroll
          for (int dx = 0; dx < 3; ++dx) {
            float xv = w[cc + dx + 3];
            a  = fmaf(wk[dx], xv, a);
            b2 = fmaf(wv[dx], xv, b2);
          }
          kacc[ro][cc] = a; vacc[ro][cc] = b2;
          if (ro == roq) {
            float qa = qacc[cc];
            #pragma unroll
            for (int dx = 0; dx < 3; ++dx)
              qa = fmaf(wq[dx], w[cc + dx + 3], qa);
            qacc[cc] = qa;
          }
        }
      }
    }
    __syncthreads();                        // sweep done (xs reads complete)
    if (ci < 5) {                           // restage next channel
      const float* xch = x + (size_t)(ci + 1) * 65536;
      for (int e = tid; e < 18 * 264; e += 256) {
        int sr = e / 264, slot = e - sr * 264;
        int xr = r0 - 1 + sr, xc = slot - 4;
        float v = 0.f;
        if ((unsigned)xr < 256u && (unsigned)xc < 256u)
          v = xch[xr * 256 + xc];
        xs[e] = v;
      }
      __syncthreads();
    }
  }

  // write K/V tiles (slot = padded_col + 1; interior pc = x1col+3) + q + pads
  {
    #pragma unroll
    for (int ro = 0; ro < 4; ++ro) {
      int lr = 4 * rq + ro;
      float4 tk = make_float4(kacc[ro][0], kacc[ro][1], kacc[ro][2], kacc[ro][3]);
      float4 tv = make_float4(vacc[ro][0], vacc[ro][1], vacc[ro][2], vacc[ro][3]);
      *(float4*)&KT[lr * 268 + 4 * tq + 4] = tk;
      *(float4*)&VT[lr * 268 + 4 * tq + 4] = tv;
    }
    float4 tQ = make_float4(qacc[0], qacc[1], qacc[2], qacc[3]);
    *(float4*)&QS[rq * 256 + 4 * tq] = tQ;
    if (tid < 96) {                         // pad cols: pc 0,1,2,259,260,261
      int lr = tid & 15, pi = tid >> 4;
      int slot = (pi < 3) ? (pi + 1) : (pi + 257);
      KT[lr * 268 + slot] = bsl[3];
      VT[lr * 268 + slot] = bsl[4];
    }
  }
  __syncthreads();

  // ---- attention at sampled pixels ---------------------------------------
  int ox  = tid & 31;
  int dy  = (tid >> 5) & 1;
  int dx  = (tid >> 6) & 1;
  int oyl = (tid >> 7) & 1;
  int wb  = 8 * ox + 4 * dx;
  int dv  = dx ? 0 : 3;
  int lrow0 = 8 * oyl + dy;
  int qrow  = 2 * oyl + dy;

  float4 qv4 = *(const float4*)&QS[qrow * 256 + wb];
  float qv0 = qv4.x, qv1 = qv4.y, qv2 = qv4.z, qv3 = qv4.w;
  float qsum = qv0 + qv1 + qv2 + qv3;

  float qk[49];
  #pragma unroll
  for (int i = 0; i < 7; ++i) {
    const float* kr = &KT[(lrow0 + i) * 268 + wb];   // B[t] ~ pc = wb-1+t
    float B[16];
    *(float4*)&B[0]  = *(const float4*)&kr[0];
    *(float4*)&B[4]  = *(const float4*)&kr[4];
    *(float4*)&B[8]  = *(const float4*)&kr[8];
    *(float4*)&B[12] = *(const float4*)&kr[12];
    float rh = rhs[i];
    #pragma unroll
    for (int j = 0; j < 7; ++j) {
      float d0 = fmaf(qv0, B[j + 1],
                 fmaf(qv1, B[j + 2],
                 fmaf(qv2, B[j + 3], qv3 * B[j + 4])));
      qk[i * 7 + j] = fmaf(qsum, rh + rws[j], d0);
    }
  }
  float m = qk[0];
  #pragma unroll
  for (int z = 1; z < 49; ++z) m = fmaxf(m, qk[z]);
  float sum = 0.f;
  #pragma unroll
  for (int z = 0; z < 49; ++z) {
    float e = __expf(qk[z] - m);
    qk[z] = e;
    sum += e;
  }
  float inv = 1.0f / sum;

  float o = 0.f;
  #pragma unroll
  for (int i = 0; i < 7; ++i) {
    const float* vr = &VT[(lrow0 + i) * 268 + wb];
    float B[16];
    *(float4*)&B[0]  = *(const float4*)&vr[0];
    *(float4*)&B[4]  = *(const float4*)&vr[4];
    *(float4*)&B[8]  = *(const float4*)&vr[8];
    *(float4*)&B[12] = *(const float4*)&vr[12];
    #pragma unroll
    for (int j = 0; j < 7; ++j)
      o = fmaf(qk[i * 7 + j], B[dv + j + 1], o);
  }
  float quarter = 0.25f * o * inv;           // this pixel's share of sc

  // reduce: dy (bit5, in-wave), dx (bit6, via LDS), then row stats
  float pairsum = quarter + __shfl_xor(quarter, 32);
  red[tid] = pairsum;
  __syncthreads();

  if ((tid & 96) == 0) {                     // dy=0,dx=0 lanes: 2x32 threads
    float scv = red[tid] + red[tid ^ 64];    // sc[c][2*b16+oyl][ox]
    float e31v = __shfl(scv, 31, 32);
    float e0v  = __shfl(scv, 0, 32);
    float rs = scv;
    #pragma unroll
    for (int off = 16; off >= 1; off >>= 1) rs += __shfl_down(rs, off, 32);
    if (ox == 0) {
      grp[oyl * 3 + 0] = rs; grp[oyl * 3 + 1] = e0v; grp[oyl * 3 + 2] = e31v;
    }
  }
  __syncthreads();

  if (tid == 0) {
    float* pa = statA + (c * 16 + b16) * 3;
    pa[0] = grp[0] + grp[3];                 // T partial
    pa[1] = grp[1] + grp[4];                 // col0 partial
    pa[2] = grp[2] + grp[5];                 // col31 partial
    if (b16 == 0) {
      statB[c * 6 + 0] = grp[0];             // r0
      statB[c * 6 + 2] = grp[1];             // e00
      statB[c * 6 + 3] = grp[2];             // e0_31
    }
    if (b16 == 15) {
      statB[c * 6 + 1] = grp[3];             // r31
      statB[c * 6 + 4] = grp[4];             // e31_0
      statB[c * 6 + 5] = grp[5];             // e31_31
    }
  }
}

// K2: pooled[oc]: reconstruct S[342] (rect-sum closed form) then 342-dot.
__global__ __launch_bounds__(64) void k_pool(
    const float* __restrict__ statA, const float* __restrict__ statB,
    const float* __restrict__ Sx,
    const float* __restrict__ bw, const float* __restrict__ bb,
    const float* __restrict__ ew, const float* __restrict__ eb,
    float* __restrict__ pooled) {
  __shared__ float Sl[342];
  int oc = blockIdx.x, lane = threadIdx.x;
  if (lane < 32) {
    int ch = lane;
    float T = 0.f, C0 = 0.f, C31 = 0.f;
    #pragma unroll
    for (int i = 0; i < 16; ++i) {
      const float* pa = statA + (ch * 16 + i) * 3;
      T += pa[0]; C0 += pa[1]; C31 += pa[2];
    }
    const float* pb = statB + ch * 6;
    float r0 = pb[0], r31 = pb[1];
    float e00 = pb[2], e0_31 = pb[3], e31_0 = pb[4], e31_31 = pb[5];
    #pragma unroll
    for (int ky = 0; ky < 3; ++ky) {
      float exR = (ky == 0) ? r31 : (ky == 2 ? r0 : 0.f);
      #pragma unroll
      for (int kx = 0; kx < 3; ++kx) {
        float exC = (kx == 0) ? C31 : (kx == 2 ? C0 : 0.f);
        float corner = 0.f;
        if (ky != 1 && kx != 1) {
          if (ky == 0) corner = (kx == 0) ? e31_31 : e31_0;
          else         corner = (kx == 0) ? e0_31  : e00;
        }
        Sl[ch * 9 + ky * 3 + kx] = T - exR - exC + corner;
      }
    }
  }
  if (lane < 54) Sl[288 + lane] = Sx[lane];
  __syncthreads();

  float acc = 0.f;
  #pragma unroll
  for (int i0 = 0; i0 < 342; i0 += 64) {
    int i = i0 + lane;
    if (i < 342) {
      float wv = (i < 288) ? ew[oc * 288 + i] : bw[oc * 54 + (i - 288)];
      acc = fmaf(wv, Sl[i], acc);
    }
  }
  #pragma unroll
  for (int off = 32; off >= 1; off >>= 1) acc += __shfl_down(acc, off);
  if (lane == 0)
    pooled[oc] = bb[oc] + eb[oc] + acc * (1.0f / 1024.0f);
}

// K3: fc head, one block (64 lanes) per class.
__global__ __launch_bounds__(64) void k_fc(
    const float* __restrict__ pooled, const float* __restrict__ fcw,
    const float* __restrict__ fcb, float* __restrict__ out) {
  int o = blockIdx.x, lane = threadIdx.x;
  float acc = 0.f;
  #pragma unroll
  for (int i0 = 0; i0 < 512; i0 += 64)
    acc = fmaf(fcw[o * 512 + i0 + lane], pooled[i0 + lane], acc);
  #pragma unroll
  for (int off = 32; off >= 1; off >>= 1) acc += __shfl_down(acc, off);
  if (lane == 0) out[o] = fcb[o] + acc;
}

extern "C" void kernel_launch(void* const* d_in, const int* in_sizes, int n_in,
                              void* d_out, int out_size, void* d_ws, size_t ws_size,
                              hipStream_t stream) {
  const float* x    = (const float*)d_in[0];
  // d_in[1] = diff_input (int, always 1) -> attention branch always taken
  const float* bw   = (const float*)d_in[2];
  const float* bb   = (const float*)d_in[3];
  const float* c1w  = (const float*)d_in[4];
  const float* c1b  = (const float*)d_in[5];
  const float* kw   = (const float*)d_in[6];
  const float* kb   = (const float*)d_in[7];
  const float* qw   = (const float*)d_in[8];
  const float* qb   = (const float*)d_in[9];
  const float* vw   = (const float*)d_in[10];
  const float* vb   = (const float*)d_in[11];
  const float* relh = (const float*)d_in[12];
  const float* relw = (const float*)d_in[13];
  const float* ew   = (const float*)d_in[14];
  const float* eb   = (const float*)d_in[15];
  const float* fcw  = (const float*)d_in[16];
  const float* fcb  = (const float*)d_in[17];

  float* ws    = (float*)d_ws;
  float* statA = ws + OFF_STATA;
  float* statB = ws + OFF_STATB;
  float* Sxb   = ws + OFF_SX;
  float* pool  = ws + OFF_P;
  float* out   = (float*)d_out;

  k_fused<<<566, 256, 0, stream>>>(x, c1w, c1b, kw, kb, qw, qb, vw, vb,
                                   relh, relw, statA, statB, Sxb);
  k_pool <<<512, 64,  0, stream>>>(statA, statB, Sxb, bw, bb, ew, eb, pool);
  k_fc   <<<20,  64,  0, stream>>>(pool, fcw, fcb, out);
}